// Round 3
// baseline (765.530 us; speedup 1.0000x reference)
//
#include <hip/hip_runtime.h>
#include <hip/hip_fp16.h>

#define BB 4096
#define NN 4096
#define GRID 256
#define TPB 1024
#define ROWS (BB / GRID)        // 16 rows of K per block
#define WAVES (TPB / 64)        // 16

// ---- grid barrier: sense-reversing, device-scope atomics (G16-safe) ----
__device__ __forceinline__ void gsync(unsigned* cnt, unsigned* gen, unsigned& lg) {
    __syncthreads();
    if (threadIdx.x == 0) {
        unsigned arrived = __hip_atomic_fetch_add(cnt, 1u, __ATOMIC_ACQ_REL,
                                                  __HIP_MEMORY_SCOPE_AGENT);
        if (arrived == GRID - 1) {
            // reset counter, then publish generation (release orders the store)
            __hip_atomic_store(cnt, 0u, __ATOMIC_RELAXED, __HIP_MEMORY_SCOPE_AGENT);
            __hip_atomic_fetch_add(gen, 1u, __ATOMIC_RELEASE, __HIP_MEMORY_SCOPE_AGENT);
        } else {
            while (__hip_atomic_load(gen, __ATOMIC_ACQUIRE, __HIP_MEMORY_SCOPE_AGENT) <= lg)
                __builtin_amdgcn_s_sleep(4);
        }
    }
    lg++;
    __syncthreads();
}

__global__ __launch_bounds__(TPB, 4) void k_coop(
        const int* __restrict__ users, const int* __restrict__ pois,
        const float* __restrict__ Dt, const float* __restrict__ poi_emb,
        const float* __restrict__ user_emb, const float* __restrict__ cap,
        float* __restrict__ out, float* __restrict__ dsum,
        float* __restrict__ vglob, float* __restrict__ part,
        unsigned* cnt, unsigned* gen) {
    // ---- LDS: 128K (K slice) + 16K scratch + ~2.2K small = 146.2 KB ----
    __shared__ __half Kl[ROWS * NN];     // this block's 16 rows of K, fp16
    __shared__ float  scr[NN];           // lut bounce / v-reduce scratch
    __shared__ float  ues[ROWS * 16];    // 16 user embeddings
    __shared__ float  wred[ROWS * WAVES];// per-wave row partials
    __shared__ float  ulds[ROWS];        // u for this block's rows

    const int t = threadIdx.x;
    const int b0 = blockIdx.x * ROWS;
    unsigned lg = 0;

    // ================= phase 0: mean(D) partial =================
    {
        const float4* D4 = (const float4*)Dt;
        float ms = 0.f;
        const int stride = GRID * TPB;
        int base = blockIdx.x * TPB + t;
        #pragma unroll
        for (int i = 0; i < (BB * NN / 4) / (GRID * TPB); i++) {   // 16
            float4 d = D4[base + i * stride];
            ms += (d.x + d.y) + (d.z + d.w);
        }
        #pragma unroll
        for (int off = 32; off > 0; off >>= 1) ms += __shfl_down(ms, off, 64);
        if ((t & 63) == 0) wred[t >> 6] = ms;
        __syncthreads();
        if (t == 0) {
            float s = 0.f;
            for (int w = 0; w < WAVES; w++) s += wred[w];
            atomicAdd(dsum, s);
        }
    }

    // ================= phase 1: build luts s[r][j] = pe[j].ue[r] into Kl ====
    if (t < ROWS * 16) {
        int r = t >> 4, d = t & 15;
        ues[t] = user_emb[(size_t)users[b0 + r] * 16 + d];
    }
    __syncthreads();
    {
        const float4* pe4 = (const float4*)poi_emb;
        float4 pe[4][4];                          // 4 j's per thread, 16 floats each
        #pragma unroll
        for (int i = 0; i < 4; i++) {
            int j = t + i * TPB;
            pe[i][0] = pe4[j * 4 + 0]; pe[i][1] = pe4[j * 4 + 1];
            pe[i][2] = pe4[j * 4 + 2]; pe[i][3] = pe4[j * 4 + 3];
        }
        for (int r = 0; r < ROWS; r++) {
            float4 u0 = *(float4*)&ues[r * 16 + 0];
            float4 u1 = *(float4*)&ues[r * 16 + 4];
            float4 u2 = *(float4*)&ues[r * 16 + 8];
            float4 u3 = *(float4*)&ues[r * 16 + 12];
            #pragma unroll
            for (int i = 0; i < 4; i++) {
                float a = pe[i][0].x*u0.x + pe[i][0].y*u0.y + pe[i][0].z*u0.z + pe[i][0].w*u0.w
                        + pe[i][1].x*u1.x + pe[i][1].y*u1.y + pe[i][1].z*u1.z + pe[i][1].w*u1.w
                        + pe[i][2].x*u2.x + pe[i][2].y*u2.y + pe[i][2].z*u2.z + pe[i][2].w*u2.w
                        + pe[i][3].x*u3.x + pe[i][3].y*u3.y + pe[i][3].z*u3.z + pe[i][3].w*u3.w;
                Kl[r * NN + t + i * TPB] = __float2half(a);
            }
        }
    }
    gsync(cnt, gen, lg);                         // publishes dsum too

    // ================= phase 2: K[r][n] = exp(5*s[r][pois] - c*Dt) =========
    {
        const float cc = 5.0f * 16777216.0f /
            __hip_atomic_load(dsum, __ATOMIC_RELAXED, __HIP_MEMORY_SCOPE_AGENT);
        const int4*   p4 = (const int4*)pois;
        const float4* d4 = (const float4*)Dt;
        int4   pidx = p4[(size_t)b0 * (NN / 4) + t];    // prefetch row 0
        float4 pdv  = d4[(size_t)b0 * (NN / 4) + t];
        for (int r = 0; r < ROWS; r++) {
            {   // copy lut row r (fp16) -> scr (fp32)
                __half2 h01 = *(__half2*)&Kl[r * NN + 4 * t];
                __half2 h23 = *(__half2*)&Kl[r * NN + 4 * t + 2];
                float2 f01 = __half22float2(h01), f23 = __half22float2(h23);
                *(float4*)&scr[4 * t] = make_float4(f01.x, f01.y, f23.x, f23.y);
            }
            int4 ci = pidx; float4 cd = pdv;
            __syncthreads();
            if (r + 1 < ROWS) {                  // prefetch next row
                pidx = p4[(size_t)(b0 + r + 1) * (NN / 4) + t];
                pdv  = d4[(size_t)(b0 + r + 1) * (NN / 4) + t];
            }
            float k0 = __expf(5.0f * scr[ci.x] - cc * cd.x);
            float k1 = __expf(5.0f * scr[ci.y] - cc * cd.y);
            float k2 = __expf(5.0f * scr[ci.z] - cc * cd.z);
            float k3 = __expf(5.0f * scr[ci.w] - cc * cd.w);
            __half2* kw = (__half2*)&Kl[r * NN + 4 * t];
            kw[0] = __floats2half2_rn(k0, k1);
            kw[1] = __floats2half2_rn(k2, k3);
            __syncthreads();
        }
    }

    // ================= phase 3: 10 Sinkhorn iterations ======================
    float vr[4] = {1.f, 1.f, 1.f, 1.f};          // v for this thread's 4 cols
    float* partme = part + (size_t)blockIdx.x * NN;
    const int wv = t >> 6, ln = t & 63;
    for (int it = 0; it < 10; it++) {
        // --- u-pass: p[r] = K[r, cols].vr, cache K strip in regs ---
        float p[ROWS];
        __half2 kc[ROWS][2];
        #pragma unroll
        for (int r = 0; r < ROWS; r++) {
            kc[r][0] = *(__half2*)&Kl[r * NN + 4 * t];
            kc[r][1] = *(__half2*)&Kl[r * NN + 4 * t + 2];
            float2 a = __half22float2(kc[r][0]);
            float2 b = __half22float2(kc[r][1]);
            p[r] = a.x * vr[0] + a.y * vr[1] + b.x * vr[2] + b.y * vr[3];
        }
        #pragma unroll
        for (int r = 0; r < ROWS; r++)
            #pragma unroll
            for (int off = 32; off > 0; off >>= 1) p[r] += __shfl_down(p[r], off, 64);
        if (ln == 0) {
            #pragma unroll
            for (int r = 0; r < ROWS; r++) wred[r * WAVES + wv] = p[r];
        }
        __syncthreads();
        if (t < ROWS) {
            float s = 0.f;
            for (int w = 0; w < WAVES; w++) s += wred[t * WAVES + w];
            ulds[t] = 1.0f / s;
        }
        __syncthreads();
        // --- v-partial: vp = sum_r u[r]*K[r, cols] ---
        float vp0 = 0.f, vp1 = 0.f, vp2 = 0.f, vp3 = 0.f;
        #pragma unroll
        for (int r = 0; r < ROWS; r++) {
            float ub = ulds[r];
            float2 a = __half22float2(kc[r][0]);
            float2 b = __half22float2(kc[r][1]);
            vp0 += ub * a.x; vp1 += ub * a.y; vp2 += ub * b.x; vp3 += ub * b.y;
        }
        ((float4*)partme)[t] = make_float4(vp0, vp1, vp2, vp3);
        gsync(cnt, gen, lg);
        // --- v-reduce: this block owns 16 columns ---
        {
            int c = t & 15, g = t >> 4;          // g in 0..63
            int col = blockIdx.x * 16 + c;
            float s = 0.f;
            #pragma unroll
            for (int q = 0; q < 4; q++)
                s += part[(size_t)(g * 4 + q) * NN + col];
            scr[g * 16 + c] = s;
        }
        __syncthreads();
        if (t < 16) {
            float s = 0.f;
            for (int g = 0; g < 64; g++) s += scr[g * 16 + t];
            int col = blockIdx.x * 16 + t;
            vglob[col] = cap[col] / s;
        }
        gsync(cnt, gen, lg);
        float4 nv = ((const float4*)vglob)[t];
        vr[0] = nv.x; vr[1] = nv.y; vr[2] = nv.z; vr[3] = nv.w;
    }

    // ================= phase 4: P = K * u * v -> out ========================
    for (int r = 0; r < ROWS; r++) {
        float ub = ulds[r];
        __half2 h0 = *(__half2*)&Kl[r * NN + 4 * t];
        __half2 h1 = *(__half2*)&Kl[r * NN + 4 * t + 2];
        float2 a = __half22float2(h0), b = __half22float2(h1);
        ((float4*)out)[(size_t)(b0 + r) * (NN / 4) + t] =
            make_float4(a.x * ub * vr[0], a.y * ub * vr[1],
                        b.x * ub * vr[2], b.y * ub * vr[3]);
    }
}

extern "C" void kernel_launch(void* const* d_in, const int* in_sizes, int n_in,
                              void* d_out, int out_size, void* d_ws, size_t ws_size,
                              hipStream_t stream) {
    const int*   users    = (const int*)d_in[0];
    const int*   pois     = (const int*)d_in[1];
    const float* Dt       = (const float*)d_in[2];
    const float* poi_emb  = (const float*)d_in[3];
    const float* user_emb = (const float*)d_in[4];
    const float* cap      = (const float*)d_in[5];
    float* out = (float*)d_out;

    float*    wsf  = (float*)d_ws;
    unsigned* cnt  = (unsigned*)d_ws;          // [0]
    unsigned* gen  = cnt + 1;                  // [1]
    float*    dsum = wsf + 2;                  // [2]
    float*    vglob = wsf + 64;                // [NN]
    float*    part  = wsf + 64 + NN;           // [GRID*NN] = 4 MB

    hipMemsetAsync(d_ws, 0, 1024, stream);     // zero cnt/gen/dsum

    void* args[] = { (void*)&users, (void*)&pois, (void*)&Dt, (void*)&poi_emb,
                     (void*)&user_emb, (void*)&cap, (void*)&out, (void*)&dsum,
                     (void*)&vglob, (void*)&part, (void*)&cnt, (void*)&gen };
    hipError_t e = hipLaunchCooperativeKernel((const void*)k_coop,
                                              dim3(GRID), dim3(TPB),
                                              args, 0, stream);
    if (e != hipSuccess) {
        // 256 blocks at 1 block/CU on 256 CUs are co-resident under plain
        // launch too; barrier is our own (no cg dependency).
        k_coop<<<dim3(GRID), dim3(TPB), 0, stream>>>(
            users, pois, Dt, poi_emb, user_emb, cap, out, dsum, vglob, part,
            cnt, gen);
    }
}

// Round 4
// 393.335 us; speedup vs baseline: 1.9463x; 1.9463x over previous
//
#include <hip/hip_runtime.h>
#include <hip/hip_fp16.h>

#define BB 4096
#define NN 4096
#define RPB 2        // rows per block in k_K

// ---------------- mean(D) reduction + v=1 init ----------------
__global__ __launch_bounds__(256) void k_mean(
        const float* __restrict__ Dt, float* __restrict__ dsum,
        float* __restrict__ v) {
    const int tid = blockIdx.x * blockDim.x + threadIdx.x;
    if (tid < NN) v[tid] = 1.0f;
    const float4* D4 = (const float4*)Dt;
    const int total4 = (BB * NN) / 4;
    float s = 0.f;
    for (int i = tid; i < total4; i += gridDim.x * blockDim.x) {
        float4 d = D4[i];
        s += (d.x + d.y) + (d.z + d.w);
    }
    #pragma unroll
    for (int off = 32; off > 0; off >>= 1) s += __shfl_down(s, off, 64);
    __shared__ float ls[4];
    if ((threadIdx.x & 63) == 0) ls[threadIdx.x >> 6] = s;
    __syncthreads();
    if (threadIdx.x == 0) atomicAdd(dsum, (ls[0] + ls[1]) + (ls[2] + ls[3]));
}

// ---------------- K = exp(5*dot - 5*D/mean), fp16, fp16 lut ----------------
__global__ __launch_bounds__(256) void k_K(
        const int* __restrict__ users, const int* __restrict__ pois,
        const float* __restrict__ Dt, const float* __restrict__ poi_emb,
        const float* __restrict__ user_emb, const float* __restrict__ dsum,
        __half* __restrict__ K) {
    __shared__ __half slut[RPB][NN];      // 16 KB -> 8 blocks/CU
    __shared__ float ues[RPB * 16];
    const int t = threadIdx.x;
    const int b0 = blockIdx.x * RPB;
    if (t < RPB * 16) {
        int r = t >> 4, d = t & 15;
        ues[t] = user_emb[(size_t)users[b0 + r] * 16 + d];
    }
    __syncthreads();
    float ue[RPB][16];
    #pragma unroll
    for (int r = 0; r < RPB; r++)
        #pragma unroll
        for (int d = 0; d < 16; d++) ue[r][d] = ues[r * 16 + d];

    const float4* pe4 = (const float4*)poi_emb;
    for (int j = t; j < NN; j += 256) {
        float4 p0 = pe4[j * 4 + 0];
        float4 p1 = pe4[j * 4 + 1];
        float4 p2 = pe4[j * 4 + 2];
        float4 p3 = pe4[j * 4 + 3];
        #pragma unroll
        for (int r = 0; r < RPB; r++) {
            float acc = p0.x*ue[r][0]  + p0.y*ue[r][1]  + p0.z*ue[r][2]  + p0.w*ue[r][3]
                      + p1.x*ue[r][4]  + p1.y*ue[r][5]  + p1.z*ue[r][6]  + p1.w*ue[r][7]
                      + p2.x*ue[r][8]  + p2.y*ue[r][9]  + p2.z*ue[r][10] + p2.w*ue[r][11]
                      + p3.x*ue[r][12] + p3.y*ue[r][13] + p3.z*ue[r][14] + p3.w*ue[r][15];
            slut[r][j] = __float2half(acc);
        }
    }
    __syncthreads();                       // lut read-only from here on
    const float cc = 5.0f * 16777216.0f / dsum[0];   // 5 / mean(D)
    #pragma unroll
    for (int r = 0; r < RPB; r++) {
        const size_t base = (size_t)(b0 + r) * NN;
        const int4*   p4 = (const int4*)(pois + base);
        const float4* d4 = (const float4*)(Dt + base);
        #pragma unroll
        for (int i = 0; i < NN / 4 / 256; i++) {     // 4
            const int q = t + i * 256;
            int4   ci = p4[q];
            float4 cd = d4[q];
            float k0 = __expf(5.0f * __half2float(slut[r][ci.x]) - cc * cd.x);
            float k1 = __expf(5.0f * __half2float(slut[r][ci.y]) - cc * cd.y);
            float k2 = __expf(5.0f * __half2float(slut[r][ci.z]) - cc * cd.z);
            float k3 = __expf(5.0f * __half2float(slut[r][ci.w]) - cc * cd.w);
            __half2* kw = (__half2*)&K[base + 4 * (size_t)q];
            kw[0] = __floats2half2_rn(k0, k1);
            kw[1] = __floats2half2_rn(k2, k3);
        }
    }
}

// ---------------- transpose Kh -> KT (64x64 fp16 tiles) ----------------
__global__ __launch_bounds__(256) void k_T(
        const __half* __restrict__ K, __half* __restrict__ KT) {
    __shared__ __half tile[64][72];       // +8 pad
    const int t = threadIdx.x;
    const int r = t >> 2;                 // 0..63
    const int q = t & 3;                  // 0..3
    const int n0 = blockIdx.x * 64;
    const int b0 = blockIdx.y * 64;
    #pragma unroll
    for (int i = 0; i < 2; i++) {
        int cseg = (q + 4 * i) * 8;
        float4 f = *(const float4*)&K[(size_t)(b0 + r) * NN + n0 + cseg];
        *(float4*)&tile[r][cseg] = f;
    }
    __syncthreads();
    #pragma unroll
    for (int i = 0; i < 2; i++) {
        int cseg = (q + 4 * i) * 8;
        __half tmp[8];
        #pragma unroll
        for (int k = 0; k < 8; k++) tmp[k] = tile[cseg + k][r];
        *(float4*)&KT[(size_t)(n0 + r) * BB + b0 + cseg] = *(float4*)tmp;
    }
}

// ---------------- row dot: 16 elems/thread over a 4096-wide fp16 row -------
__device__ __forceinline__ float rowdot(const __half* __restrict__ row,
                                        const float* __restrict__ w, int t) {
    const float4* r4 = (const float4*)row;
    float4 h0 = r4[t], h1 = r4[256 + t];
    const __half2* a = (const __half2*)&h0;
    const __half2* b = (const __half2*)&h1;
    const float4* w4 = (const float4*)w;
    float4 wa0 = w4[2 * t], wa1 = w4[2 * t + 1];
    float4 wb0 = w4[512 + 2 * t], wb1 = w4[512 + 2 * t + 1];
    float s = 0.f; float2 f;
    f = __half22float2(a[0]); s += f.x * wa0.x + f.y * wa0.y;
    f = __half22float2(a[1]); s += f.x * wa0.z + f.y * wa0.w;
    f = __half22float2(a[2]); s += f.x * wa1.x + f.y * wa1.y;
    f = __half22float2(a[3]); s += f.x * wa1.z + f.y * wa1.w;
    f = __half22float2(b[0]); s += f.x * wb0.x + f.y * wb0.y;
    f = __half22float2(b[1]); s += f.x * wb0.z + f.y * wb0.w;
    f = __half22float2(b[2]); s += f.x * wb1.x + f.y * wb1.y;
    f = __half22float2(b[3]); s += f.x * wb1.z + f.y * wb1.w;
    #pragma unroll
    for (int off = 32; off > 0; off >>= 1) s += __shfl_down(s, off, 64);
    __shared__ float ls[4];
    if ((t & 63) == 0) ls[t >> 6] = s;
    __syncthreads();
    return (ls[0] + ls[1]) + (ls[2] + ls[3]);
}

// u[b] = 1 / (K[b,:].v)
__global__ __launch_bounds__(256) void k_u(
        const __half* __restrict__ K, const float* __restrict__ v,
        float* __restrict__ u) {
    float s = rowdot(K + (size_t)blockIdx.x * NN, v, threadIdx.x);
    if (threadIdx.x == 0) u[blockIdx.x] = 1.0f / s;
}

// v[n] = cap[n] / (KT[n,:].u)
__global__ __launch_bounds__(256) void k_v(
        const __half* __restrict__ KT, const float* __restrict__ u,
        const float* __restrict__ cap, float* __restrict__ v) {
    float s = rowdot(KT + (size_t)blockIdx.x * BB, u, threadIdx.x);
    if (threadIdx.x == 0) v[blockIdx.x] = cap[blockIdx.x] / s;
}

// ---------------- P = K * u[b] * v[n] ----------------
__global__ __launch_bounds__(256) void k_P_h(
        const __half* __restrict__ K, const float* __restrict__ u,
        const float* __restrict__ v, float* __restrict__ P) {
    const int i = blockIdx.x * 256 + threadIdx.x;  // half8 index
    const int e = i * 8;
    const int b = e >> 12;
    const int col = e & 4095;
    float4 raw = ((const float4*)K)[i];
    const __half2* h = (const __half2*)&raw;
    const float ub = u[b];
    float4 v0 = ((const float4*)v)[col >> 2];
    float4 v1 = ((const float4*)v)[(col >> 2) + 1];
    float2 f0 = __half22float2(h[0]);
    float2 f1 = __half22float2(h[1]);
    float2 f2 = __half22float2(h[2]);
    float2 f3 = __half22float2(h[3]);
    ((float4*)P)[e >> 2]       = make_float4(f0.x*ub*v0.x, f0.y*ub*v0.y,
                                             f1.x*ub*v0.z, f1.y*ub*v0.w);
    ((float4*)P)[(e >> 2) + 1] = make_float4(f2.x*ub*v1.x, f2.y*ub*v1.y,
                                             f3.x*ub*v1.z, f3.y*ub*v1.w);
}

extern "C" void kernel_launch(void* const* d_in, const int* in_sizes, int n_in,
                              void* d_out, int out_size, void* d_ws, size_t ws_size,
                              hipStream_t stream) {
    const int*   users    = (const int*)d_in[0];
    const int*   pois     = (const int*)d_in[1];
    const float* Dt       = (const float*)d_in[2];
    const float* poi_emb  = (const float*)d_in[3];
    const float* user_emb = (const float*)d_in[4];
    const float* cap      = (const float*)d_in[5];
    float* out = (float*)d_out;

    float*  wsf  = (float*)d_ws;
    float*  dsum = wsf;                        // [1]
    float*  u    = wsf + 64;                   // [BB]
    float*  v    = wsf + 64 + BB;              // [NN]
    __half* Kh   = (__half*)(wsf + 64 + BB + NN);   // [BB*NN] fp16 = 33.5 MB
    __half* KT   = (__half*)d_out;             // first 33.5 MB of out; dead before k_P

    hipMemsetAsync(dsum, 0, sizeof(float), stream);
    k_mean<<<2048, 256, 0, stream>>>(Dt, dsum, v);
    k_K<<<BB / RPB, 256, 0, stream>>>(users, pois, Dt, poi_emb, user_emb, dsum, Kh);
    k_T<<<dim3(NN / 64, BB / 64), 256, 0, stream>>>(Kh, KT);
    for (int it = 0; it < 10; it++) {
        k_u<<<BB, 256, 0, stream>>>(Kh, v, u);
        k_v<<<NN, 256, 0, stream>>>(KT, u, cap, v);
    }
    k_P_h<<<(BB * NN / 8) / 256, 256, 0, stream>>>(Kh, u, v, out);
}